// Round 4
// baseline (287.432 us; speedup 1.0000x reference)
//
#include <hip/hip_runtime.h>
#include <math.h>

#define N_ATOMS  50000
#define N_NBRS   32
#define N_GAUSS  25
#define RCUT     5.0f
#define TT       4096      // nearest-neighbor filter table nodes
#define MAXZ     100
#define PI_F     3.14159265358979323846f

typedef unsigned int   uint_t;
typedef unsigned short ushort_t;
typedef _Float16 f16;
typedef f16   f16x2 __attribute__((ext_vector_type(2)));
typedef f16   f16x8 __attribute__((ext_vector_type(8)));
typedef float f32x4 __attribute__((ext_vector_type(4)));

__device__ __forceinline__ float ssp(float x) {
  return fmaxf(x, 0.0f) + log1pf(__expf(-fabsf(x))) - 0.69314718055994531f;
}
__device__ __forceinline__ f16x2 bch(uint_t u) {
  return __builtin_bit_cast(f16x2, u);
}
// swizzled element offset into a [16][128] f16 LDS tile (8-elem chunk XOR row)
__device__ __forceinline__ int swz(int m, int e) {
  return m * 128 + ((((e >> 3) ^ m) & 15) << 3) + (e & 7);
}

// ---- prep 1: nearest table tabh[i][f] = f16( W(r_i)*fcut(r_i) ), r_i = i*RCUT/(TT-1)
__global__ void build_table_kernel(const float* __restrict__ fw1,
                                   const float* __restrict__ fb1,
                                   const float* __restrict__ fw2,
                                   const float* __restrict__ fb2,
                                   f16* __restrict__ tabh,
                                   float* __restrict__ out) {
  const int i = blockIdx.x;
  const int f = threadIdx.x;
  if (i == 0 && f == 0) out[0] = 0.0f;   // re-zero output accumulator every launch
  const float r = (float)i * (RCUT / (float)(TT - 1));
  const float delta = RCUT / (float)(N_GAUSS - 1);
  const float coeff = -0.5f / (delta * delta);
  float h = fb1[f];
  #pragma unroll
  for (int g = 0; g < N_GAUSS; ++g) {
    const float d = r - (float)g * delta;
    h = fmaf(__expf(coeff * d * d), fw1[g * 128 + f], h);
  }
  h = ssp(h);
  __shared__ float hl[128];
  hl[f] = h;
  __syncthreads();
  float w = fb2[f];
  for (int j = 0; j < 128; j += 4) {
    const float4 hv = *reinterpret_cast<const float4*>(&hl[j]);
    w = fmaf(hv.x, fw2[(j + 0) * 128 + f], w);
    w = fmaf(hv.y, fw2[(j + 1) * 128 + f], w);
    w = fmaf(hv.z, fw2[(j + 2) * 128 + f], w);
    w = fmaf(hv.w, fw2[(j + 3) * 128 + f], w);
  }
  const float fc = (r < RCUT) ? 0.5f * (__cosf(r * PI_F / RCUT) + 1.0f) : 0.0f;
  tabh[i * 128 + f] = (f16)(w * fc);
}

// ---- prep 2 (merged): weight transposes + ytab[z] = embed[z] @ in2f (100 rows)
__global__ void prep_merged_kernel(const float* __restrict__ w1,
                                   const float* __restrict__ w2,
                                   const float* __restrict__ mw1,
                                   const float* __restrict__ embed,
                                   const float* __restrict__ in2f,
                                   f16* __restrict__ w1ht,
                                   f16* __restrict__ w2ht,
                                   f16* __restrict__ mw1ht,
                                   f16* __restrict__ ytab) {
  const int c = blockIdx.x;    // output column / z index
  const int i = threadIdx.x;   // input row
  w1ht[c * 128 + i] = (f16)w1[i * 128 + c];
  w2ht[c * 128 + i] = (f16)w2[i * 128 + c];
  if (c < 64) mw1ht[c * 128 + i] = (f16)mw1[i * 64 + c];
  if (c < MAXZ) {              // uniform per block -> barrier is safe
    __shared__ float xs[128];
    xs[i] = embed[c * 128 + i];
    __syncthreads();
    float acc = 0.0f;
    for (int j = 0; j < 128; j += 4) {
      const float4 xv = *reinterpret_cast<const float4*>(&xs[j]);
      acc = fmaf(xv.x, in2f[(j + 0) * 128 + i], acc);
      acc = fmaf(xv.y, in2f[(j + 1) * 128 + i], acc);
      acc = fmaf(xv.z, in2f[(j + 2) * 128 + i], acc);
      acc = fmaf(xv.w, in2f[(j + 3) * 128 + i], acc);
    }
    ytab[c * 128 + i] = (f16)acc;
  }
}

// ---- main fused kernel: 256 threads, 16 atoms/block ----
__global__ void __launch_bounds__(256, 6)
schnet_main_kernel(const float* __restrict__ dR,
                   const int* __restrict__ Z,
                   const int* __restrict__ nbr,
                   const float* __restrict__ embed,
                   const f16* __restrict__ tabh,
                   const f16* __restrict__ ytab,
                   const f16* __restrict__ w1ht, const float* __restrict__ b1,
                   const f16* __restrict__ w2ht, const float* __restrict__ b2,
                   const f16* __restrict__ mw1ht, const float* __restrict__ mb1,
                   const float* __restrict__ mw2, const float* __restrict__ mb2,
                   float* __restrict__ out) {
  const int tid = threadIdx.x;
  const int wv  = tid >> 6;          // wave 0..3
  const int l   = tid & 63;
  const int a0  = blockIdx.x * 16;
  __shared__ int2  s_pk[16 * N_NBRS];   // 4 KB: {tab_row_byte, ytab_row_byte}
  __shared__ f16   sA[16 * 128];        // 4 KB swizzled activations
  __shared__ f16   sB[16 * 128];        // 4 KB swizzled activations
  __shared__ int   sZ[16];
  __shared__ float sRed[4];

  // -- stage per-pair row offsets (coalesced dR/nbr; Z gather L2-hit) --
  const float scale = (float)(TT - 1) / RCUT;
  #pragma unroll
  for (int t0 = 0; t0 < 2; ++t0) {
    const int t = tid + t0 * 256;
    const float r = dR[a0 * N_NBRS + t];
    const int  nb = nbr[a0 * N_NBRS + t];
    int i0 = (int)(r * scale + 0.5f);
    i0 = min(i0, TT - 1);
    const int z = Z[nb];
    s_pk[t] = make_int2(i0 << 8, z << 8);   // 256 B per row (128 x f16)
  }
  if (tid < 16) sZ[tid] = Z[a0 + tid];
  __syncthreads();

  // -- cfconv: wave owns atoms m0..m0+3; half-wave owns pair parity p;
  //    lane covers 4 channels (8 B) per load --
  const int m0 = wv * 4;
  const int p  = l >> 5;          // 0: even k, 1: odd k
  const int cl = l & 31;
  const int choff = cl * 8;       // 4 ch * 2 B
  const char* tabc = (const char*)tabh;
  const char* ytc  = (const char*)ytab;

  f32x4 agg[4];
  #pragma unroll
  for (int j = 0; j < 4; ++j) agg[j] = (f32x4){0.f, 0.f, 0.f, 0.f};

  uint2 twA, ybA, twB, ybB;

#define CF_ISSUE(S, j, s) { \
    const int2 pk = s_pk[(m0 + (j)) * N_NBRS + 2 * (s) + p]; \
    tw##S = *(const uint2*)(tabc + pk.x + choff); \
    yb##S = *(const uint2*)(ytc  + pk.y + choff); }

#define CF_CONSUME(S, j) { \
    const f16x2 w0 = bch(tw##S.x), w1v = bch(tw##S.y); \
    const f16x2 y0 = bch(yb##S.x), y1v = bch(yb##S.y); \
    agg[j][0] = fmaf((float)y0[0],  (float)w0[0],  agg[j][0]); \
    agg[j][1] = fmaf((float)y0[1],  (float)w0[1],  agg[j][1]); \
    agg[j][2] = fmaf((float)y1v[0], (float)w1v[0], agg[j][2]); \
    agg[j][3] = fmaf((float)y1v[1], (float)w1v[1], agg[j][3]); }

  #pragma unroll
  for (int j = 0; j < 4; ++j) {
    CF_ISSUE(A, j, 0)
    #pragma unroll
    for (int s = 0; s < 8; ++s) {
      CF_ISSUE(B, j, 2 * s + 1)
      CF_CONSUME(A, j)
      if (s < 7) CF_ISSUE(A, j, 2 * s + 2)
      CF_CONSUME(B, j)
    }
  }
#undef CF_ISSUE
#undef CF_CONSUME

  // combine even/odd-k halves; lanes 0-31 write 4 ch (8 B) per atom
  #pragma unroll
  for (int j = 0; j < 4; ++j) {
    #pragma unroll
    for (int c = 0; c < 4; ++c) agg[j][c] += __shfl_xor(agg[j][c], 32, 64);
  }
  if (p == 0) {
    #pragma unroll
    for (int j = 0; j < 4; ++j) {
      const int m = m0 + j;
      const int e = cl * 4;
      const int off = m * 128 + ((((e >> 3) ^ m) & 15) << 3) + (e & 7);
      uint2 pk;
      pk.x = __builtin_bit_cast(uint_t, __builtin_amdgcn_cvt_pkrtz(agg[j][0], agg[j][1]));
      pk.y = __builtin_bit_cast(uint_t, __builtin_amdgcn_cvt_pkrtz(agg[j][2], agg[j][3]));
      *(uint2*)&sA[off] = pk;
    }
  }
  __syncthreads();

  const int rc = l & 15;
  const int qk = l >> 4;
#define AFRAG(SRC, k0) (*(const f16x8*)&SRC[rc * 128 + (((((k0) >> 3) + qk) ^ rc) & 15) * 8])

  // -- f2out layer 1: h1 = ssp(agg @ w1 + b1); wave covers cols wv*32..+31 --
  f32x4 acc[2];
  #pragma unroll
  for (int t = 0; t < 2; ++t) {
    const float b = b1[wv * 32 + t * 16 + rc];
    acc[t] = (f32x4){b, b, b, b};
  }
  #pragma unroll
  for (int k0 = 0; k0 < 128; k0 += 32) {
    const f16x8 af = AFRAG(sA, k0);
    #pragma unroll
    for (int t = 0; t < 2; ++t) {
      const int c = wv * 32 + t * 16 + rc;
      const f16x8 bf = *(const f16x8*)&w1ht[c * 128 + k0 + qk * 8];
      acc[t] = __builtin_amdgcn_mfma_f32_16x16x32_f16(af, bf, acc[t], 0, 0, 0);
    }
  }
  #pragma unroll
  for (int t = 0; t < 2; ++t) {
    const int c = wv * 32 + t * 16 + rc;
    #pragma unroll
    for (int r = 0; r < 4; ++r) {
      sB[swz(qk * 4 + r, c)] = (f16)ssp(acc[t][r]);
    }
  }
  __syncthreads();

  // -- f2out layer 2 + residual: xnew = embed[Z] + (h1 @ w2 + b2) --
  #pragma unroll
  for (int t = 0; t < 2; ++t) {
    const float b = b2[wv * 32 + t * 16 + rc];
    acc[t] = (f32x4){b, b, b, b};
  }
  #pragma unroll
  for (int k0 = 0; k0 < 128; k0 += 32) {
    const f16x8 af = AFRAG(sB, k0);
    #pragma unroll
    for (int t = 0; t < 2; ++t) {
      const int c = wv * 32 + t * 16 + rc;
      const f16x8 bf = *(const f16x8*)&w2ht[c * 128 + k0 + qk * 8];
      acc[t] = __builtin_amdgcn_mfma_f32_16x16x32_f16(af, bf, acc[t], 0, 0, 0);
    }
  }
  __syncthreads();   // all sB reads done before sA overwrite below
  #pragma unroll
  for (int t = 0; t < 2; ++t) {
    const int c = wv * 32 + t * 16 + rc;
    #pragma unroll
    for (int r = 0; r < 4; ++r) {
      const int m = qk * 4 + r;
      const float x = embed[(size_t)sZ[m] * 128 + c] + acc[t][r];
      sA[swz(m, c)] = (f16)x;
    }
  }
  __syncthreads();

  // -- MLP layer 1: 128 -> 64; wave covers cols wv*16..+15 --
  const int c1 = wv * 16 + rc;
  const float bm = mb1[c1];
  f32x4 a2 = (f32x4){bm, bm, bm, bm};
  #pragma unroll
  for (int k0 = 0; k0 < 128; k0 += 32) {
    const f16x8 af = AFRAG(sA, k0);
    const f16x8 bf = *(const f16x8*)&mw1ht[c1 * 128 + k0 + qk * 8];
    a2 = __builtin_amdgcn_mfma_f32_16x16x32_f16(af, bf, a2, 0, 0, 0);
  }

  // -- MLP layer 2 (64 -> 1) + global sum --
  const float cm = mw2[c1];
  float v = 0.0f;
  #pragma unroll
  for (int r = 0; r < 4; ++r) v = fmaf(ssp(a2[r]), cm, v);
  #pragma unroll
  for (int o = 1; o < 64; o <<= 1) v += __shfl_xor(v, o, 64);
  if (l == 0) sRed[wv] = v;
  __syncthreads();
  if (tid == 0) {
    atomicAdd(out, 20.0f * (sRed[0] + sRed[1] + sRed[2] + sRed[3] + 16.0f * mb2[0]));
  }
#undef AFRAG
}

extern "C" void kernel_launch(void* const* d_in, const int* in_sizes, int n_in,
                              void* d_out, int out_size, void* d_ws, size_t ws_size,
                              hipStream_t stream) {
  const float* dR    = (const float*)d_in[0];
  const int*   Z     = (const int*)  d_in[1];
  const int*   nbr   = (const int*)  d_in[2];
  const float* embed = (const float*)d_in[3];
  const float* fw1   = (const float*)d_in[4];
  const float* fb1   = (const float*)d_in[5];
  const float* fw2   = (const float*)d_in[6];
  const float* fb2   = (const float*)d_in[7];
  const float* in2f  = (const float*)d_in[8];
  const float* w1    = (const float*)d_in[9];
  const float* b1    = (const float*)d_in[10];
  const float* w2    = (const float*)d_in[11];
  const float* b2    = (const float*)d_in[12];
  const float* mw1   = (const float*)d_in[13];
  const float* mb1   = (const float*)d_in[14];
  const float* mw2   = (const float*)d_in[15];
  const float* mb2   = (const float*)d_in[16];
  float* out = (float*)d_out;

  char* ws = (char*)d_ws;
  f16* tabh  = (f16*)ws;                                   // 1 MB
  f16* ytab  = (f16*)(ws + (size_t)1088 * 1024);           // 25.6 KB
  f16* w1ht  = (f16*)(ws + (size_t)1152 * 1024);           // 32 KB
  f16* w2ht  = (f16*)(ws + (size_t)1216 * 1024);           // 32 KB
  f16* mw1ht = (f16*)(ws + (size_t)1280 * 1024);           // 16 KB

  build_table_kernel<<<TT, 128, 0, stream>>>(fw1, fb1, fw2, fb2, tabh, out);
  prep_merged_kernel<<<128, 128, 0, stream>>>(w1, w2, mw1, embed, in2f,
                                              w1ht, w2ht, mw1ht, ytab);
  schnet_main_kernel<<<N_ATOMS / 16, 256, 0, stream>>>(dR, Z, nbr, embed,
      tabh, ytab, w1ht, b1, w2ht, b2, mw1ht, mb1, mw2, mb2, out);
}

// Round 5
// 116.768 us; speedup vs baseline: 2.4616x; 2.4616x over previous
//
#include <hip/hip_runtime.h>
#include <math.h>

#define N_ATOMS  50000
#define N_NBRS   32
#define N_GAUSS  25
#define RCUT     5.0f
#define TT       4096      // nearest-neighbor filter table nodes
#define TROWS    32        // table rows per build block
#define MAXZ     100
#define PI_F     3.14159265358979323846f

typedef unsigned int   uint_t;
typedef unsigned short ushort_t;
typedef _Float16 f16;
typedef f16   f16x2 __attribute__((ext_vector_type(2)));
typedef f16   f16x4 __attribute__((ext_vector_type(4)));
typedef f16   f16x8 __attribute__((ext_vector_type(8)));
typedef float f32x4 __attribute__((ext_vector_type(4)));

__device__ __forceinline__ float ssp(float x) {
  return fmaxf(x, 0.0f) + log1pf(__expf(-fabsf(x))) - 0.69314718055994531f;
}
__device__ __forceinline__ f16x2 bch(uint_t u) {
  return __builtin_bit_cast(f16x2, u);
}
// swizzled element offset into a [16][128] f16 LDS tile (8-elem chunk XOR row)
__device__ __forceinline__ int swz(int m, int e) {
  return m * 128 + ((((e >> 3) ^ m) & 15) << 3) + (e & 7);
}

// ---- prep 1: nearest table tabh[i][f] = f16( W(r_i)*fcut(r_i) ), r_i = i*RCUT/(TT-1)
// 128 blocks x 256 threads, 32 rows/block; fw2 + H staged in LDS; no spills.
__global__ void __launch_bounds__(256, 2)
build_table_kernel(const float* __restrict__ fw1,
                   const float* __restrict__ fb1,
                   const float* __restrict__ fw2,
                   const float* __restrict__ fb2,
                   f16* __restrict__ tabh,
                   float* __restrict__ out) {
  const int tid = threadIdx.x;
  const int i0  = blockIdx.x * TROWS;
  if (blockIdx.x == 0 && tid == 0) out[0] = 0.0f;  // re-zero accumulator every launch

  __shared__ float sW2[128 * 128];       // 64 KB, fw2 row-major [k][f]
  __shared__ float sH[TROWS][128];       // 16 KB, hidden activations

  // stage fw2
  #pragma unroll
  for (int t = 0; t < 16; ++t) {
    const int e = tid + t * 256;
    ((float4*)sW2)[e] = ((const float4*)fw2)[e];
  }

  // phase 1: H[row][f] = ssp(gauss(r_row) . fw1[:,f] + fb1[f])
  // 256 threads = 128 f-cols x 2 row-halves of 16 rows
  {
    const int f  = tid & 127;
    const int rh = (tid >> 7) * (TROWS / 2);
    const float delta = RCUT / (float)(N_GAUSS - 1);
    const float coeff = -0.5f / (delta * delta);
    const float b1v = fb1[f];
    for (int j = 0; j < TROWS / 2; ++j) {
      const float r = (float)(i0 + rh + j) * (RCUT / (float)(TT - 1));
      float h = b1v;
      #pragma unroll
      for (int g = 0; g < N_GAUSS; ++g) {
        const float d = r - (float)g * delta;
        h = fmaf(__expf(coeff * d * d), fw1[g * 128 + f], h);
      }
      sH[rh + j][f] = ssp(h);
    }
  }
  __syncthreads();

  // phase 2: tab[row][c] = H[row][:] @ fw2[:,c] + fb2[c], 4 rows x 4 cols per thread
  {
    const int c0 = (tid & 31) * 4;        // column quad
    const int rg = (tid >> 5) * 4;        // row group
    f32x4 acc[4];
    const float4 bv = *(const float4*)&fb2[c0];
    #pragma unroll
    for (int j = 0; j < 4; ++j) acc[j] = (f32x4){bv.x, bv.y, bv.z, bv.w};
    for (int k = 0; k < 128; ++k) {
      const float4 wv = *(const float4*)&sW2[k * 128 + c0];
      #pragma unroll
      for (int j = 0; j < 4; ++j) {
        const float hv = sH[rg + j][k];
        acc[j][0] = fmaf(hv, wv.x, acc[j][0]);
        acc[j][1] = fmaf(hv, wv.y, acc[j][1]);
        acc[j][2] = fmaf(hv, wv.z, acc[j][2]);
        acc[j][3] = fmaf(hv, wv.w, acc[j][3]);
      }
    }
    #pragma unroll
    for (int j = 0; j < 4; ++j) {
      const int i = i0 + rg + j;
      const float r = (float)i * (RCUT / (float)(TT - 1));
      const float fc = (r < RCUT) ? 0.5f * (__cosf(r * PI_F / RCUT) + 1.0f) : 0.0f;
      f16x4 o;
      #pragma unroll
      for (int c = 0; c < 4; ++c) o[c] = (f16)(acc[j][c] * fc);
      *(f16x4*)&tabh[i * 128 + c0] = o;
    }
  }
}

// ---- prep 2 (merged): weight transposes + ytab[z] = embed[z] @ in2f (100 rows)
__global__ void prep_merged_kernel(const float* __restrict__ w1,
                                   const float* __restrict__ w2,
                                   const float* __restrict__ mw1,
                                   const float* __restrict__ embed,
                                   const float* __restrict__ in2f,
                                   f16* __restrict__ w1ht,
                                   f16* __restrict__ w2ht,
                                   f16* __restrict__ mw1ht,
                                   f16* __restrict__ ytab) {
  const int c = blockIdx.x;    // output column / z index
  const int i = threadIdx.x;   // input row
  w1ht[c * 128 + i] = (f16)w1[i * 128 + c];
  w2ht[c * 128 + i] = (f16)w2[i * 128 + c];
  if (c < 64) mw1ht[c * 128 + i] = (f16)mw1[i * 64 + c];
  if (c < MAXZ) {              // uniform per block -> barrier is safe
    __shared__ float xs[128];
    xs[i] = embed[c * 128 + i];
    __syncthreads();
    float acc = 0.0f;
    for (int j = 0; j < 128; j += 4) {
      const float4 xv = *reinterpret_cast<const float4*>(&xs[j]);
      acc = fmaf(xv.x, in2f[(j + 0) * 128 + i], acc);
      acc = fmaf(xv.y, in2f[(j + 1) * 128 + i], acc);
      acc = fmaf(xv.z, in2f[(j + 2) * 128 + i], acc);
      acc = fmaf(xv.w, in2f[(j + 3) * 128 + i], acc);
    }
    ytab[c * 128 + i] = (f16)acc;
  }
}

// ---- main fused kernel: 256 threads, 16 atoms/block ----
__global__ void __launch_bounds__(256, 6)
schnet_main_kernel(const float* __restrict__ dR,
                   const int* __restrict__ Z,
                   const int* __restrict__ nbr,
                   const float* __restrict__ embed,
                   const f16* __restrict__ tabh,
                   const f16* __restrict__ ytab,
                   const f16* __restrict__ w1ht, const float* __restrict__ b1,
                   const f16* __restrict__ w2ht, const float* __restrict__ b2,
                   const f16* __restrict__ mw1ht, const float* __restrict__ mb1,
                   const float* __restrict__ mw2, const float* __restrict__ mb2,
                   float* __restrict__ out) {
  const int tid = threadIdx.x;
  const int wv  = tid >> 6;          // wave 0..3
  const int l   = tid & 63;
  const int a0  = blockIdx.x * 16;
  __shared__ int2  s_pk[16 * N_NBRS];   // 4 KB: {tab_row_byte, ytab_row_byte}
  __shared__ f16   sA[16 * 128];        // 4 KB swizzled activations
  __shared__ f16   sB[16 * 128];        // 4 KB swizzled activations
  __shared__ int   sZ[16];
  __shared__ float sRed[4];

  // -- stage per-pair row offsets (coalesced dR/nbr; Z gather L2-hit) --
  const float scale = (float)(TT - 1) / RCUT;
  #pragma unroll
  for (int t0 = 0; t0 < 2; ++t0) {
    const int t = tid + t0 * 256;
    const float r = dR[a0 * N_NBRS + t];
    const int  nb = nbr[a0 * N_NBRS + t];
    int i0 = (int)(r * scale + 0.5f);
    i0 = min(i0, TT - 1);
    const int z = Z[nb];
    s_pk[t] = make_int2(i0 << 8, z << 8);   // 256 B per row (128 x f16)
  }
  if (tid < 16) sZ[tid] = Z[a0 + tid];
  __syncthreads();

  // -- cfconv: wave owns atoms m0..m0+3; half-wave owns pair parity p;
  //    lane covers 4 channels (8 B) per load --
  const int m0 = wv * 4;
  const int p  = l >> 5;          // 0: even k, 1: odd k
  const int cl = l & 31;
  const int choff = cl * 8;       // 4 ch * 2 B
  const char* tabc = (const char*)tabh;
  const char* ytc  = (const char*)ytab;

  f32x4 agg[4];
  #pragma unroll
  for (int j = 0; j < 4; ++j) agg[j] = (f32x4){0.f, 0.f, 0.f, 0.f};

  uint2 twA, ybA, twB, ybB;

#define CF_ISSUE(S, j, s) { \
    const int2 pk = s_pk[(m0 + (j)) * N_NBRS + 2 * (s) + p]; \
    tw##S = *(const uint2*)(tabc + pk.x + choff); \
    yb##S = *(const uint2*)(ytc  + pk.y + choff); }

#define CF_CONSUME(S, j) { \
    const f16x2 w0 = bch(tw##S.x), w1v = bch(tw##S.y); \
    const f16x2 y0 = bch(yb##S.x), y1v = bch(yb##S.y); \
    agg[j][0] = fmaf((float)y0[0],  (float)w0[0],  agg[j][0]); \
    agg[j][1] = fmaf((float)y0[1],  (float)w0[1],  agg[j][1]); \
    agg[j][2] = fmaf((float)y1v[0], (float)w1v[0], agg[j][2]); \
    agg[j][3] = fmaf((float)y1v[1], (float)w1v[1], agg[j][3]); }

  #pragma unroll
  for (int j = 0; j < 4; ++j) {
    CF_ISSUE(A, j, 0)
    #pragma unroll
    for (int s = 0; s < 8; ++s) {
      CF_ISSUE(B, j, 2 * s + 1)
      CF_CONSUME(A, j)
      if (s < 7) CF_ISSUE(A, j, 2 * s + 2)
      CF_CONSUME(B, j)
    }
  }
#undef CF_ISSUE
#undef CF_CONSUME

  // combine even/odd-k halves; lanes 0-31 write 4 ch (8 B) per atom
  #pragma unroll
  for (int j = 0; j < 4; ++j) {
    #pragma unroll
    for (int c = 0; c < 4; ++c) agg[j][c] += __shfl_xor(agg[j][c], 32, 64);
  }
  if (p == 0) {
    #pragma unroll
    for (int j = 0; j < 4; ++j) {
      const int m = m0 + j;
      const int e = cl * 4;
      const int off = m * 128 + ((((e >> 3) ^ m) & 15) << 3) + (e & 7);
      uint2 pk;
      pk.x = __builtin_bit_cast(uint_t, __builtin_amdgcn_cvt_pkrtz(agg[j][0], agg[j][1]));
      pk.y = __builtin_bit_cast(uint_t, __builtin_amdgcn_cvt_pkrtz(agg[j][2], agg[j][3]));
      *(uint2*)&sA[off] = pk;
    }
  }
  __syncthreads();

  const int rc = l & 15;
  const int qk = l >> 4;
#define AFRAG(SRC, k0) (*(const f16x8*)&SRC[rc * 128 + (((((k0) >> 3) + qk) ^ rc) & 15) * 8])

  // -- f2out layer 1: h1 = ssp(agg @ w1 + b1); wave covers cols wv*32..+31 --
  f32x4 acc[2];
  #pragma unroll
  for (int t = 0; t < 2; ++t) {
    const float b = b1[wv * 32 + t * 16 + rc];
    acc[t] = (f32x4){b, b, b, b};
  }
  #pragma unroll
  for (int k0 = 0; k0 < 128; k0 += 32) {
    const f16x8 af = AFRAG(sA, k0);
    #pragma unroll
    for (int t = 0; t < 2; ++t) {
      const int c = wv * 32 + t * 16 + rc;
      const f16x8 bf = *(const f16x8*)&w1ht[c * 128 + k0 + qk * 8];
      acc[t] = __builtin_amdgcn_mfma_f32_16x16x32_f16(af, bf, acc[t], 0, 0, 0);
    }
  }
  #pragma unroll
  for (int t = 0; t < 2; ++t) {
    const int c = wv * 32 + t * 16 + rc;
    #pragma unroll
    for (int r = 0; r < 4; ++r) {
      sB[swz(qk * 4 + r, c)] = (f16)ssp(acc[t][r]);
    }
  }
  __syncthreads();

  // -- f2out layer 2 + residual: xnew = embed[Z] + (h1 @ w2 + b2) --
  #pragma unroll
  for (int t = 0; t < 2; ++t) {
    const float b = b2[wv * 32 + t * 16 + rc];
    acc[t] = (f32x4){b, b, b, b};
  }
  #pragma unroll
  for (int k0 = 0; k0 < 128; k0 += 32) {
    const f16x8 af = AFRAG(sB, k0);
    #pragma unroll
    for (int t = 0; t < 2; ++t) {
      const int c = wv * 32 + t * 16 + rc;
      const f16x8 bf = *(const f16x8*)&w2ht[c * 128 + k0 + qk * 8];
      acc[t] = __builtin_amdgcn_mfma_f32_16x16x32_f16(af, bf, acc[t], 0, 0, 0);
    }
  }
  __syncthreads();   // all sB reads done before sA overwrite below
  #pragma unroll
  for (int t = 0; t < 2; ++t) {
    const int c = wv * 32 + t * 16 + rc;
    #pragma unroll
    for (int r = 0; r < 4; ++r) {
      const int m = qk * 4 + r;
      const float x = embed[(size_t)sZ[m] * 128 + c] + acc[t][r];
      sA[swz(m, c)] = (f16)x;
    }
  }
  __syncthreads();

  // -- MLP layer 1: 128 -> 64; wave covers cols wv*16..+15 --
  const int c1 = wv * 16 + rc;
  const float bm = mb1[c1];
  f32x4 a2 = (f32x4){bm, bm, bm, bm};
  #pragma unroll
  for (int k0 = 0; k0 < 128; k0 += 32) {
    const f16x8 af = AFRAG(sA, k0);
    const f16x8 bf = *(const f16x8*)&mw1ht[c1 * 128 + k0 + qk * 8];
    a2 = __builtin_amdgcn_mfma_f32_16x16x32_f16(af, bf, a2, 0, 0, 0);
  }

  // -- MLP layer 2 (64 -> 1) + global sum --
  const float cm = mw2[c1];
  float v = 0.0f;
  #pragma unroll
  for (int r = 0; r < 4; ++r) v = fmaf(ssp(a2[r]), cm, v);
  #pragma unroll
  for (int o = 1; o < 64; o <<= 1) v += __shfl_xor(v, o, 64);
  if (l == 0) sRed[wv] = v;
  __syncthreads();
  if (tid == 0) {
    atomicAdd(out, 20.0f * (sRed[0] + sRed[1] + sRed[2] + sRed[3] + 16.0f * mb2[0]));
  }
#undef AFRAG
}

extern "C" void kernel_launch(void* const* d_in, const int* in_sizes, int n_in,
                              void* d_out, int out_size, void* d_ws, size_t ws_size,
                              hipStream_t stream) {
  const float* dR    = (const float*)d_in[0];
  const int*   Z     = (const int*)  d_in[1];
  const int*   nbr   = (const int*)  d_in[2];
  const float* embed = (const float*)d_in[3];
  const float* fw1   = (const float*)d_in[4];
  const float* fb1   = (const float*)d_in[5];
  const float* fw2   = (const float*)d_in[6];
  const float* fb2   = (const float*)d_in[7];
  const float* in2f  = (const float*)d_in[8];
  const float* w1    = (const float*)d_in[9];
  const float* b1    = (const float*)d_in[10];
  const float* w2    = (const float*)d_in[11];
  const float* b2    = (const float*)d_in[12];
  const float* mw1   = (const float*)d_in[13];
  const float* mb1   = (const float*)d_in[14];
  const float* mw2   = (const float*)d_in[15];
  const float* mb2   = (const float*)d_in[16];
  float* out = (float*)d_out;

  char* ws = (char*)d_ws;
  f16* tabh  = (f16*)ws;                                   // 1 MB
  f16* ytab  = (f16*)(ws + (size_t)1088 * 1024);           // 25.6 KB
  f16* w1ht  = (f16*)(ws + (size_t)1152 * 1024);           // 32 KB
  f16* w2ht  = (f16*)(ws + (size_t)1216 * 1024);           // 32 KB
  f16* mw1ht = (f16*)(ws + (size_t)1280 * 1024);           // 16 KB

  build_table_kernel<<<TT / TROWS, 256, 0, stream>>>(fw1, fb1, fw2, fb2, tabh, out);
  prep_merged_kernel<<<128, 128, 0, stream>>>(w1, w2, mw1, embed, in2f,
                                              w1ht, w2ht, mw1ht, ytab);
  schnet_main_kernel<<<N_ATOMS / 16, 256, 0, stream>>>(dR, Z, nbr, embed,
      tabh, ytab, w1ht, b1, w2ht, b2, mw1ht, mb1, mw2, mb2, out);
}